// Round 4
// baseline (214.157 us; speedup 1.0000x reference)
//
#include <hip/hip_runtime.h>
#include <math.h>

// NoisyTopkRouter, all-f32.
// x[ntok,384] @ {w_route,w_noise}[8,384]^T -> 16 logits/token,
// noisy = logit + noise*softplus(noise_logit), top-2 of 8, sparse softmax.
// Output: [ntok*8 probs f32 | ntok*2 indices-as-f32].
//
// R4: R3 was latency-bound (occupancy 21.8%, VALUBusy 15%) — grid of 512 blocks
// capped us at 8 waves/CU. Now 16 d-slices x 4 tokens/thread -> 4096 waves
// (16/CU), x-prefetch in the K-loop, and a partitioned reduction (keep-half by
// token bit via DPP quad_perm on the VALU pipe; only xor4/xor8 touch LDS pipe):
// 80 shuffles/thread vs 256 naive.

constexpr int D = 384;

__device__ __forceinline__ float dpp_xor1(float v) {   // lane ^ 1, quad_perm [1,0,3,2]
    return __int_as_float(__builtin_amdgcn_update_dpp(
        0, __float_as_int(v), 0xB1, 0xF, 0xF, true));
}
__device__ __forceinline__ float dpp_xor2(float v) {   // lane ^ 2, quad_perm [2,3,0,1]
    return __int_as_float(__builtin_amdgcn_update_dpp(
        0, __float_as_int(v), 0x4E, 0xF, 0xF, true));
}
__device__ __forceinline__ float swz_xor4(float v) {   // ds_swizzle BitMode xor 4
    return __int_as_float(__builtin_amdgcn_ds_swizzle(__float_as_int(v), 0x101F));
}
__device__ __forceinline__ float swz_xor8(float v) {   // ds_swizzle BitMode xor 8
    return __int_as_float(__builtin_amdgcn_ds_swizzle(__float_as_int(v), 0x201F));
}

__global__ __launch_bounds__(256, 4) void noisy_topk_router_f32(
    const float* __restrict__ x,        // [ntok,384]
    const float* __restrict__ noise,    // [ntok,8]
    const float* __restrict__ w_route,  // [8,384]
    const float* __restrict__ b_route,  // [8]
    const float* __restrict__ w_noise,  // [8,384]
    const float* __restrict__ b_noise,  // [8]
    float* __restrict__ out,            // [ntok*8 | ntok*2]
    int ntok)
{
    __shared__ float w_lds[16 * D];   // rows: e=0..7 route, e=8..15 noise
    __shared__ float bias[16];

    const int tid = threadIdx.x;

    // stage weights: 2 x 3072 floats = 2 x 768 float4; 256 threads x 3 each
#pragma unroll
    for (int r = 0; r < 3; ++r) {
        int i = (tid + 256 * r) * 4;                       // < 3072
        *(float4*)(w_lds + i)        = *(const float4*)(w_route + i);
        *(float4*)(w_lds + 3072 + i) = *(const float4*)(w_noise + i);
    }
    if (tid < 8)       bias[tid] = b_route[tid];
    else if (tid < 16) bias[tid] = b_noise[tid - 8];
    __syncthreads();

    const int wave = tid >> 6;
    const int lane = tid & 63;
    const int tg   = lane >> 4;       // token-group 0..3 (16 lanes each)
    const int c    = lane & 15;       // d-slice 0..15
    // wave covers 16 tokens; block covers 64
    const int tok0 = blockIdx.x * 64 + wave * 16 + tg * 4;

    float acc[4][16];
#pragma unroll
    for (int t = 0; t < 4; ++t)
#pragma unroll
        for (int e = 0; e < 16; ++e) acc[t][e] = 0.f;

    // per j: lane c covers d = j*64 + c*4 .. +4  (16 lanes = 256B contiguous)
    const float* xr = x + (size_t)tok0 * D + c * 4;

    float4 xv[4], xn[4];
#pragma unroll
    for (int t = 0; t < 4; ++t) xv[t] = *(const float4*)(xr + t * D);

#pragma unroll 1
    for (int j = 0; j < 6; ++j) {
        const int jn = (j < 5) ? (j + 1) * 64 : 0;   // uniform; last prefetch is a dummy re-read
#pragma unroll
        for (int t = 0; t < 4; ++t) xn[t] = *(const float4*)(xr + t * D + jn);

        const float* wj = w_lds + j * 64 + c * 4;
#pragma unroll
        for (int e = 0; e < 16; ++e) {
            float4 wv = *(const float4*)(wj + e * D);
            acc[0][e] += xv[0].x * wv.x + xv[0].y * wv.y + xv[0].z * wv.z + xv[0].w * wv.w;
            acc[1][e] += xv[1].x * wv.x + xv[1].y * wv.y + xv[1].z * wv.z + xv[1].w * wv.w;
            acc[2][e] += xv[2].x * wv.x + xv[2].y * wv.y + xv[2].z * wv.z + xv[2].w * wv.w;
            acc[3][e] += xv[3].x * wv.x + xv[3].y * wv.y + xv[3].z * wv.z + xv[3].w * wv.w;
        }
#pragma unroll
        for (int t = 0; t < 4; ++t) xv[t] = xn[t];
    }

    // partitioned reduction over the 16 d-slices.
    // step1 (xor1): keep tokens with (t&1)==(c&1)   -> 2 tokens/lane
    // step2 (xor2): keep token  with (t>>1)==(c>>1&1) -> token c&3
    // steps xor4, xor8: plain reduce of the 16 expert sums.
    const bool b0 = (c & 1), b1 = (c >> 1) & 1;
    float a2[2][16];
#pragma unroll
    for (int u = 0; u < 2; ++u)
#pragma unroll
        for (int e = 0; e < 16; ++e) {
            float s = b0 ? acc[2 * u][e]     : acc[2 * u + 1][e];   // send
            float k = b0 ? acc[2 * u + 1][e] : acc[2 * u][e];       // keep
            a2[u][e] = k + dpp_xor1(s);
        }
    float a1[16];
#pragma unroll
    for (int e = 0; e < 16; ++e) {
        float s = b1 ? a2[0][e] : a2[1][e];
        float k = b1 ? a2[1][e] : a2[0][e];
        a1[e] = k + dpp_xor2(s);
    }
#pragma unroll
    for (int e = 0; e < 16; ++e) a1[e] += swz_xor4(a1[e]);
#pragma unroll
    for (int e = 0; e < 16; ++e) a1[e] += swz_xor8(a1[e]);
    // lane c now holds token tok0 + (c&3), all 16 expert sums (c>=4 duplicates)

    if (c < 4) {
        const int token = tok0 + c;
        float4 n0 = *(const float4*)(noise + (size_t)token * 8);
        float4 n1 = *(const float4*)(noise + (size_t)token * 8 + 4);
        float nz[8] = {n0.x, n0.y, n0.z, n0.w, n1.x, n1.y, n1.z, n1.w};

        float noisy[8];
#pragma unroll
        for (int e = 0; e < 8; ++e) {
            float lg = a1[e] + bias[e];
            float nl = a1[8 + e] + bias[8 + e];
            // stable softplus: max(z,0) + log1p(exp(-|z|))
            float sp = fmaxf(nl, 0.f) + log1pf(expf(-fabsf(nl)));
            noisy[e] = lg + nz[e] * sp;
        }

        // top-2, jax.lax.top_k tie-break: earliest index wins ties
        float v0 = noisy[0]; int i0 = 0;
#pragma unroll
        for (int e = 1; e < 8; ++e)
            if (noisy[e] > v0) { v0 = noisy[e]; i0 = e; }
        float v1 = -INFINITY; int i1 = 0;
#pragma unroll
        for (int e = 0; e < 8; ++e)
            if (e != i0 && noisy[e] > v1) { v1 = noisy[e]; i1 = e; }

        // 2-way softmax (other experts exactly 0)
        float ex  = expf(v1 - v0);       // v1 <= v0
        float inv = 1.f / (1.f + ex);
        float p0  = inv;
        float p1  = ex * inv;

        float pr[8];
#pragma unroll
        for (int e = 0; e < 8; ++e)
            pr[e] = (e == i0) ? p0 : ((e == i1) ? p1 : 0.f);

        float* orow = out + (size_t)token * 8;
        *(float4*)(orow)     = make_float4(pr[0], pr[1], pr[2], pr[3]);
        *(float4*)(orow + 4) = make_float4(pr[4], pr[5], pr[6], pr[7]);

        *(float2*)(out + (size_t)ntok * 8 + (size_t)token * 2) =
            make_float2((float)i0, (float)i1);
    }
}

extern "C" void kernel_launch(void* const* d_in, const int* in_sizes, int n_in,
                              void* d_out, int out_size, void* d_ws, size_t ws_size,
                              hipStream_t stream) {
    const float* x       = (const float*)d_in[0];
    const float* noise   = (const float*)d_in[1];
    const float* w_route = (const float*)d_in[2];
    const float* b_route = (const float*)d_in[3];
    const float* w_noise = (const float*)d_in[4];
    const float* b_noise = (const float*)d_in[5];
    float* out = (float*)d_out;

    const int ntok   = in_sizes[0] / D;   // 65536
    const int blocks = ntok / 64;         // 64 tokens per 256-thread block

    hipLaunchKernelGGL(noisy_topk_router_f32, dim3(blocks), dim3(256), 0, stream,
                       x, noise, w_route, b_route, w_noise, b_noise, out, ntok);
}

// Round 5
// 170.805 us; speedup vs baseline: 1.2538x; 1.2538x over previous
//
#include <hip/hip_runtime.h>
#include <math.h>

// NoisyTopkRouter, all-f32.
// x[ntok,384] @ {w_route,w_noise}[8,384]^T -> 16 logits/token,
// noisy = logit + noise*softplus(noise_logit), top-2 of 8, sparse softmax.
// Output: [ntok*8 probs f32 | ntok*2 indices-as-f32].
//
// R5: R3/R4 regressed from SCRATCH SPILL (WRITE_SIZE 59/180 MB vs 2.6 ideal):
// acc[4][16]+prefetch exceeded the VGPR cap. Now T=2 tokens x 8 d-slices:
// acc[2][16]=32 floats + 2x2 float4 prefetch ~= 70 VGPRs, no spill, and still
// 4096 waves (16/CU). Weight LDS reads are 8-way same-address broadcast
// (free); reduction is partitioned (keep-half by token bit at xor1, DPP) so
// no dynamic acc indexing ever exists.

constexpr int D = 384;

__device__ __forceinline__ float dpp_xor1(float v) {   // lane ^ 1, quad_perm [1,0,3,2]
    return __int_as_float(__builtin_amdgcn_update_dpp(
        0, __float_as_int(v), 0xB1, 0xF, 0xF, true));
}
__device__ __forceinline__ float dpp_xor2(float v) {   // lane ^ 2, quad_perm [2,3,0,1]
    return __int_as_float(__builtin_amdgcn_update_dpp(
        0, __float_as_int(v), 0x4E, 0xF, 0xF, true));
}
__device__ __forceinline__ float swz_xor4(float v) {   // ds_swizzle BitMode xor 4
    return __int_as_float(__builtin_amdgcn_ds_swizzle(__float_as_int(v), 0x101F));
}

__global__ __launch_bounds__(256, 4) void noisy_topk_router_f32(
    const float* __restrict__ x,        // [ntok,384]
    const float* __restrict__ noise,    // [ntok,8]
    const float* __restrict__ w_route,  // [8,384]
    const float* __restrict__ b_route,  // [8]
    const float* __restrict__ w_noise,  // [8,384]
    const float* __restrict__ b_noise,  // [8]
    float* __restrict__ out,            // [ntok*8 | ntok*2]
    int ntok)
{
    __shared__ float w_lds[16 * D];   // rows: e=0..7 route, e=8..15 noise
    __shared__ float bias[16];

    const int tid = threadIdx.x;

    // stage weights: 2 x 3072 floats = 2 x 768 float4; 256 threads x 3 each
#pragma unroll
    for (int r = 0; r < 3; ++r) {
        int i = (tid + 256 * r) * 4;                       // < 3072
        *(float4*)(w_lds + i)        = *(const float4*)(w_route + i);
        *(float4*)(w_lds + 3072 + i) = *(const float4*)(w_noise + i);
    }
    if (tid < 8)       bias[tid] = b_route[tid];
    else if (tid < 16) bias[tid] = b_noise[tid - 8];
    __syncthreads();

    const int wave = tid >> 6;
    const int lane = tid & 63;
    const int tg   = lane >> 3;       // token-group 0..7 (8 lanes each)
    const int c    = lane & 7;        // d-slice 0..7
    // group handles 2 tokens; wave covers 16; block covers 64
    const int tok0 = blockIdx.x * 64 + wave * 16 + tg * 2;

    float acc[2][16];
#pragma unroll
    for (int t = 0; t < 2; ++t)
#pragma unroll
        for (int e = 0; e < 16; ++e) acc[t][e] = 0.f;

    // per j: lane c covers d = j*32 + c*4 .. +4 (8 lanes = 128B contiguous)
    const float* xr = x + (size_t)tok0 * D + c * 4;

    float4 xv[2], xn[2];
    xv[0] = *(const float4*)(xr);
    xv[1] = *(const float4*)(xr + D);

#pragma unroll 1
    for (int j = 0; j < 12; ++j) {
        const int jn = (j < 11) ? (j + 1) * 32 : 0;   // last prefetch: dummy re-read
        xn[0] = *(const float4*)(xr + jn);
        xn[1] = *(const float4*)(xr + D + jn);

        const float* wj = w_lds + j * 32 + c * 4;
#pragma unroll
        for (int e = 0; e < 16; ++e) {
            float4 wv = *(const float4*)(wj + e * D);   // 8-way broadcast across groups
            acc[0][e] += xv[0].x * wv.x + xv[0].y * wv.y + xv[0].z * wv.z + xv[0].w * wv.w;
            acc[1][e] += xv[1].x * wv.x + xv[1].y * wv.y + xv[1].z * wv.z + xv[1].w * wv.w;
        }
        xv[0] = xn[0];
        xv[1] = xn[1];
    }

    // partitioned reduction over the 8 d-slices:
    // xor1: keep the token matching bit0 of c (DPP, VALU pipe)
    // xor2 (DPP) + xor4 (ds_swizzle): plain reduce of the 16 sums.
    const bool b0 = (c & 1);
    float a1[16];
#pragma unroll
    for (int e = 0; e < 16; ++e) {
        float s = b0 ? acc[0][e] : acc[1][e];   // send the token we don't keep
        float k = b0 ? acc[1][e] : acc[0][e];   // keep token tok0 + (c&1)
        a1[e] = k + dpp_xor1(s);
    }
#pragma unroll
    for (int e = 0; e < 16; ++e) a1[e] += dpp_xor2(a1[e]);
#pragma unroll
    for (int e = 0; e < 16; ++e) a1[e] += swz_xor4(a1[e]);
    // lanes c<2 hold full sums for token tok0 + c

    if (c < 2) {
        const int token = tok0 + c;
        float4 n0 = *(const float4*)(noise + (size_t)token * 8);
        float4 n1 = *(const float4*)(noise + (size_t)token * 8 + 4);
        float nz[8] = {n0.x, n0.y, n0.z, n0.w, n1.x, n1.y, n1.z, n1.w};

        float noisy[8];
#pragma unroll
        for (int e = 0; e < 8; ++e) {
            float lg = a1[e] + bias[e];
            float nl = a1[8 + e] + bias[8 + e];
            // stable softplus: max(z,0) + log1p(exp(-|z|))
            float sp = fmaxf(nl, 0.f) + log1pf(expf(-fabsf(nl)));
            noisy[e] = lg + nz[e] * sp;
        }

        // top-2, jax.lax.top_k tie-break: earliest index wins ties
        float v0 = noisy[0]; int i0 = 0;
#pragma unroll
        for (int e = 1; e < 8; ++e)
            if (noisy[e] > v0) { v0 = noisy[e]; i0 = e; }
        float v1 = -INFINITY; int i1 = 0;
#pragma unroll
        for (int e = 0; e < 8; ++e)
            if (e != i0 && noisy[e] > v1) { v1 = noisy[e]; i1 = e; }

        // 2-way softmax (other experts exactly 0)
        float ex  = expf(v1 - v0);       // v1 <= v0
        float inv = 1.f / (1.f + ex);
        float p0  = inv;
        float p1  = ex * inv;

        float pr[8];
#pragma unroll
        for (int e = 0; e < 8; ++e)
            pr[e] = (e == i0) ? p0 : ((e == i1) ? p1 : 0.f);

        float* orow = out + (size_t)token * 8;
        *(float4*)(orow)     = make_float4(pr[0], pr[1], pr[2], pr[3]);
        *(float4*)(orow + 4) = make_float4(pr[4], pr[5], pr[6], pr[7]);

        *(float2*)(out + (size_t)ntok * 8 + (size_t)token * 2) =
            make_float2((float)i0, (float)i1);
    }
}

extern "C" void kernel_launch(void* const* d_in, const int* in_sizes, int n_in,
                              void* d_out, int out_size, void* d_ws, size_t ws_size,
                              hipStream_t stream) {
    const float* x       = (const float*)d_in[0];
    const float* noise   = (const float*)d_in[1];
    const float* w_route = (const float*)d_in[2];
    const float* b_route = (const float*)d_in[3];
    const float* w_noise = (const float*)d_in[4];
    const float* b_noise = (const float*)d_in[5];
    float* out = (float*)d_out;

    const int ntok   = in_sizes[0] / D;   // 65536
    const int blocks = ntok / 64;         // 64 tokens per 256-thread block

    hipLaunchKernelGGL(noisy_topk_router_f32, dim3(blocks), dim3(256), 0, stream,
                       x, noise, w_route, b_route, w_noise, b_noise, out, ntok);
}

// Round 6
// 164.562 us; speedup vs baseline: 1.3014x; 1.0379x over previous
//
#include <hip/hip_runtime.h>
#include <math.h>

// NoisyTopkRouter, all-f32.
// x[ntok,384] @ {w_route,w_noise}[8,384]^T -> 16 logits/token,
// noisy = logit + noise*softplus(noise_logit), top-2 of 8, sparse softmax.
// Output: [ntok*8 probs f32 | ntok*2 indices-as-f32].
//
// R6: R2 vs R5 showed the limiter is neither LDS (halving ds_reads: no change)
// nor VALU nor HBM BW (1.8 TB/s) -> latency-bound with ~2 outstanding loads
// per wave and a vmcnt(0) stall every j-iter. Now the K-loop is 4 supersteps
// x 3 chunks: each superstep prefetches the NEXT 6 float4 x-loads (both
// tokens) into registers before consuming the current 6 -> 6 outstanding
// loads/wave, 4 waits instead of 12. ~110 VGPR, no spill at the (256,4) cap.

constexpr int D = 384;

__device__ __forceinline__ float dpp_xor1(float v) {   // lane ^ 1, quad_perm [1,0,3,2]
    return __int_as_float(__builtin_amdgcn_update_dpp(
        0, __float_as_int(v), 0xB1, 0xF, 0xF, true));
}
__device__ __forceinline__ float dpp_xor2(float v) {   // lane ^ 2, quad_perm [2,3,0,1]
    return __int_as_float(__builtin_amdgcn_update_dpp(
        0, __float_as_int(v), 0x4E, 0xF, 0xF, true));
}
__device__ __forceinline__ float swz_xor4(float v) {   // ds_swizzle BitMode xor 4
    return __int_as_float(__builtin_amdgcn_ds_swizzle(__float_as_int(v), 0x101F));
}

__global__ __launch_bounds__(256, 4) void noisy_topk_router_f32(
    const float* __restrict__ x,        // [ntok,384]
    const float* __restrict__ noise,    // [ntok,8]
    const float* __restrict__ w_route,  // [8,384]
    const float* __restrict__ b_route,  // [8]
    const float* __restrict__ w_noise,  // [8,384]
    const float* __restrict__ b_noise,  // [8]
    float* __restrict__ out,            // [ntok*8 | ntok*2]
    int ntok)
{
    __shared__ float w_lds[16 * D];   // rows: e=0..7 route, e=8..15 noise
    __shared__ float bias[16];

    const int tid = threadIdx.x;

    // stage weights: 2 x 3072 floats = 2 x 768 float4; 256 threads x 3 each
#pragma unroll
    for (int r = 0; r < 3; ++r) {
        int i = (tid + 256 * r) * 4;                       // < 3072
        *(float4*)(w_lds + i)        = *(const float4*)(w_route + i);
        *(float4*)(w_lds + 3072 + i) = *(const float4*)(w_noise + i);
    }
    if (tid < 8)       bias[tid] = b_route[tid];
    else if (tid < 16) bias[tid] = b_noise[tid - 8];
    __syncthreads();

    const int wave = tid >> 6;
    const int lane = tid & 63;
    const int tg   = lane >> 3;       // token-group 0..7 (8 lanes each)
    const int c    = lane & 7;        // d-slice 0..7
    // group handles 2 tokens; wave covers 16; block covers 64
    const int tok0 = blockIdx.x * 64 + wave * 16 + tg * 2;

    float acc[2][16];
#pragma unroll
    for (int t = 0; t < 2; ++t)
#pragma unroll
        for (int e = 0; e < 16; ++e) acc[t][e] = 0.f;

    // chunk q (0..11): lane c covers d = q*32 + c*4 .. +4
    const float* xr = x + (size_t)tok0 * D + c * 4;

    float4 xa[2][3], xb[2][3];
#pragma unroll
    for (int qq = 0; qq < 3; ++qq) {
        xa[0][qq] = *(const float4*)(xr + qq * 32);
        xa[1][qq] = *(const float4*)(xr + D + qq * 32);
    }

#pragma unroll
    for (int s = 0; s < 4; ++s) {
        // prefetch next superstep (s=3: dummy re-read of chunk 0..2)
        const int qn = (s < 3) ? (s + 1) * 3 : 0;
#pragma unroll
        for (int qq = 0; qq < 3; ++qq) {
            xb[0][qq] = *(const float4*)(xr + (qn + qq) * 32);
            xb[1][qq] = *(const float4*)(xr + D + (qn + qq) * 32);
        }
        // consume current superstep from registers
#pragma unroll
        for (int qq = 0; qq < 3; ++qq) {
            const int q = s * 3 + qq;
            const float* wj = w_lds + q * 32 + c * 4;
#pragma unroll
            for (int e = 0; e < 16; ++e) {
                float4 wv = *(const float4*)(wj + e * D);   // 8-way broadcast
                acc[0][e] += xa[0][qq].x * wv.x + xa[0][qq].y * wv.y
                           + xa[0][qq].z * wv.z + xa[0][qq].w * wv.w;
                acc[1][e] += xa[1][qq].x * wv.x + xa[1][qq].y * wv.y
                           + xa[1][qq].z * wv.z + xa[1][qq].w * wv.w;
            }
        }
#pragma unroll
        for (int qq = 0; qq < 3; ++qq) {
            xa[0][qq] = xb[0][qq];
            xa[1][qq] = xb[1][qq];
        }
    }

    // partitioned reduction over the 8 d-slices:
    // xor1: keep the token matching bit0 of c (DPP, VALU pipe)
    // xor2 (DPP) + xor4 (ds_swizzle): plain reduce of the 16 sums.
    const bool b0 = (c & 1);
    float a1[16];
#pragma unroll
    for (int e = 0; e < 16; ++e) {
        float s = b0 ? acc[0][e] : acc[1][e];   // send the token we don't keep
        float k = b0 ? acc[1][e] : acc[0][e];   // keep token tok0 + (c&1)
        a1[e] = k + dpp_xor1(s);
    }
#pragma unroll
    for (int e = 0; e < 16; ++e) a1[e] += dpp_xor2(a1[e]);
#pragma unroll
    for (int e = 0; e < 16; ++e) a1[e] += swz_xor4(a1[e]);
    // lanes c<2 hold full sums for token tok0 + c

    if (c < 2) {
        const int token = tok0 + c;
        float4 n0 = *(const float4*)(noise + (size_t)token * 8);
        float4 n1 = *(const float4*)(noise + (size_t)token * 8 + 4);
        float nz[8] = {n0.x, n0.y, n0.z, n0.w, n1.x, n1.y, n1.z, n1.w};

        float noisy[8];
#pragma unroll
        for (int e = 0; e < 8; ++e) {
            float lg = a1[e] + bias[e];
            float nl = a1[8 + e] + bias[8 + e];
            // stable softplus: max(z,0) + log1p(exp(-|z|))
            float sp = fmaxf(nl, 0.f) + log1pf(expf(-fabsf(nl)));
            noisy[e] = lg + nz[e] * sp;
        }

        // top-2, jax.lax.top_k tie-break: earliest index wins ties
        float v0 = noisy[0]; int i0 = 0;
#pragma unroll
        for (int e = 1; e < 8; ++e)
            if (noisy[e] > v0) { v0 = noisy[e]; i0 = e; }
        float v1 = -INFINITY; int i1 = 0;
#pragma unroll
        for (int e = 0; e < 8; ++e)
            if (e != i0 && noisy[e] > v1) { v1 = noisy[e]; i1 = e; }

        // 2-way softmax (other experts exactly 0)
        float ex  = expf(v1 - v0);       // v1 <= v0
        float inv = 1.f / (1.f + ex);
        float p0  = inv;
        float p1  = ex * inv;

        float pr[8];
#pragma unroll
        for (int e = 0; e < 8; ++e)
            pr[e] = (e == i0) ? p0 : ((e == i1) ? p1 : 0.f);

        float* orow = out + (size_t)token * 8;
        *(float4*)(orow)     = make_float4(pr[0], pr[1], pr[2], pr[3]);
        *(float4*)(orow + 4) = make_float4(pr[4], pr[5], pr[6], pr[7]);

        *(float2*)(out + (size_t)ntok * 8 + (size_t)token * 2) =
            make_float2((float)i0, (float)i1);
    }
}

extern "C" void kernel_launch(void* const* d_in, const int* in_sizes, int n_in,
                              void* d_out, int out_size, void* d_ws, size_t ws_size,
                              hipStream_t stream) {
    const float* x       = (const float*)d_in[0];
    const float* noise   = (const float*)d_in[1];
    const float* w_route = (const float*)d_in[2];
    const float* b_route = (const float*)d_in[3];
    const float* w_noise = (const float*)d_in[4];
    const float* b_noise = (const float*)d_in[5];
    float* out = (float*)d_out;

    const int ntok   = in_sizes[0] / D;   // 65536
    const int blocks = ntok / 64;         // 64 tokens per 256-thread block

    hipLaunchKernelGGL(noisy_topk_router_f32, dim3(blocks), dim3(256), 0, stream,
                       x, noise, w_route, b_route, w_noise, b_noise, out, ntok);
}